// Round 3
// baseline (686.451 us; speedup 1.0000x reference)
//
#include <hip/hip_runtime.h>
#include <math.h>

// ---------------------------------------------------------------------------
// GPT transformer block, internal bf16 compute / fp32 accumulate.
// B=4, T=2048, D=1024 (8192 rows), 3D=3072, 4D=4096.
// Round 9: 8-phase GEMM now software-pipelines LDS fragment reads one phase
// ahead (counted lgkmcnt(4), never 0 in-loop) so the DS pipe overlaps the
// MFMA pipe (r8 measured them serialized: 1284 cyc/phase = 580 DS + 621 MFMA).
// B frags read once per tile at p0 (single buffer), A double-buffered.
// All six GEMMs (qkv/scores/pv/proj/fc/fc2) now use this kernel; scores uses
// triangular tile enumeration, pv uses per-block K clamp (softmax store mask
// widened to t|255 so 256-wide K tiles read stored zeros).
// ---------------------------------------------------------------------------

typedef unsigned short u16;
typedef __attribute__((ext_vector_type(8))) short bf16x8;   // 8 bf16 = 4 VGPRs
typedef __attribute__((ext_vector_type(8))) unsigned short u16x8;
typedef __attribute__((ext_vector_type(4))) float f32x4;

#define DEV __device__ __forceinline__

#define GLOAD_LDS16(gp, lp)                                                     \
    __builtin_amdgcn_global_load_lds(                                           \
        (const __attribute__((address_space(1))) void*)(gp),                    \
        (__attribute__((address_space(3))) void*)(lp), 16, 0, 0)

// inline-asm LDS b128 read: invisible to SIInsertWaitcnts; pair with explicit
// counted s_waitcnt lgkmcnt + sched_barrier(0) before use (rule #18).
#define DSR128(dst_, p_)                                                        \
    asm volatile("ds_read_b128 %0, %1"                                          \
                 : "=v"(dst_)                                                   \
                 : "v"((unsigned)(unsigned long long)                           \
                       (__attribute__((address_space(3))) const void*)(p_)))

DEV float bf2f(u16 h) {
    union { unsigned u; float f; } t; t.u = ((unsigned)h) << 16; return t.f;
}
DEV u16 f2bf(float f) {
    union { unsigned u; float f; } t; t.f = f;
    unsigned u = t.u;
    return (u16)((u + 0x7FFFu + ((u >> 16) & 1u)) >> 16);   // round-nearest-even
}
DEV float loadIn(const void* p, long i, int isbf) {
    return isbf ? bf2f(((const u16*)p)[i]) : ((const float*)p)[i];
}
// gelu(x) = 0.5x(1+tanh(u)) = x * sigmoid(2u)
DEV float gelu_fast(float x) {
    float u = 1.5957691216057308f * (x + 0.044715f * x * x * x);  // 2*sqrt(2/pi)
    return x * __builtin_amdgcn_rcpf(1.0f + __expf(-u));
}

DEV float waveSum(float v) {
    #pragma unroll
    for (int o = 32; o > 0; o >>= 1) v += __shfl_down(v, o, 64);
    return v;
}
DEV float waveMax(float v) {
    #pragma unroll
    for (int o = 32; o > 0; o >>= 1) v = fmaxf(v, __shfl_down(v, o, 64));
    return v;
}

template <bool IS_MAX>
DEV float blockReduce(float v) {
    __shared__ float tmp[5];
    __syncthreads();
    v = IS_MAX ? waveMax(v) : waveSum(v);
    int lane = threadIdx.x & 63, w = threadIdx.x >> 6;
    if (lane == 0) tmp[w] = v;
    __syncthreads();
    if (threadIdx.x == 0) {
        float r = tmp[0];
        for (int i = 1; i < 4; i++) r = IS_MAX ? fmaxf(r, tmp[i]) : (r + tmp[i]);
        tmp[4] = r;
    }
    __syncthreads();
    return tmp[4];
}

// ---------------- dtype detection (1 block) --------------------------------
__global__ void detect_dtype(const u16* __restrict__ xr, int* __restrict__ flag) {
    const int tid = threadIdx.x;           // 256
    int cnt = 0;
    #pragma unroll
    for (int i = 0; i < 16; i++) {
        unsigned u = xr[2 * (tid + 256 * i)];      // even u16 indices
        unsigned e = (u >> 7) & 0xFF;              // bf16 exponent field
        cnt += (e >= 100 && e <= 140) ? 1 : 0;     // ~always for bf16 N(0,1)
    }
    __shared__ int sh[4];
    #pragma unroll
    for (int o = 32; o > 0; o >>= 1) cnt += __shfl_down(cnt, o, 64);
    if ((tid & 63) == 0) sh[tid >> 6] = cnt;
    __syncthreads();
    if (tid == 0) flag[0] = (sh[0] + sh[1] + sh[2] + sh[3] > 2048) ? 1 : 0;
}

// ---------------- LayerNorm (D=1024, one 256-thread block per row) ---------
template <bool RAW_IN>
__global__ void ln_kernel(const void* __restrict__ x, const void* __restrict__ g,
                          const void* __restrict__ b, u16* __restrict__ out,
                          const int* __restrict__ flagp) {
    const int isbf = *flagp;
    const int inbf = RAW_IN ? isbf : 1;
    const long base = (long)blockIdx.x * 1024;
    const int tid = threadIdx.x;
    float v[4];
    #pragma unroll
    for (int j = 0; j < 4; j++) v[j] = loadIn(x, base + tid + 256 * j, inbf);
    float mu = blockReduce<false>(v[0] + v[1] + v[2] + v[3]) * (1.0f / 1024.0f);
    float d[4], sq = 0.f;
    #pragma unroll
    for (int j = 0; j < 4; j++) { d[j] = v[j] - mu; sq += d[j] * d[j]; }
    float var = blockReduce<false>(sq) * (1.0f / 1024.0f);
    float rstd = rsqrtf(var + 1e-5f);
    #pragma unroll
    for (int j = 0; j < 4; j++) {
        int c = tid + 256 * j;
        out[base + c] = f2bf(d[j] * rstd * loadIn(g, c, isbf) + loadIn(b, c, isbf));
    }
}

// ---------------- 32x32 transpose -> bf16 ----------------------------------
__global__ void transpose_to_bf16(const void* __restrict__ in, int ldin, long inBatch,
                                  u16* __restrict__ out, int ldout, long outBatch,
                                  const int* __restrict__ flagp) {
    __shared__ u16 tile[32][33];
    const int isbf = flagp ? *flagp : 1;
    const long ibase = (long)blockIdx.z * inBatch;
    out += (long)blockIdx.z * outBatch;
    const int bc = blockIdx.x * 32, br = blockIdx.y * 32;
    const int tx = threadIdx.x & 31, ty = threadIdx.x >> 5;   // 256 thr
    #pragma unroll
    for (int i = 0; i < 32; i += 8)
        tile[ty + i][tx] = f2bf(loadIn(in, ibase + (long)(br + ty + i) * ldin + bc + tx, isbf));
    __syncthreads();
    #pragma unroll
    for (int i = 0; i < 32; i += 8)
        out[(long)(bc + ty + i) * ldout + br + tx] = tile[tx][ty + i];
}

// ---------------- 256x256 8-phase pipelined GEMM ---------------------------
// C[M,N] = A[M,K] @ (Bt[N,K])^T (+epilogue). M%256==0, N%256==0, K%64==0.
// 512 threads = 8 waves (2M x 4N), per-wave C tile 128x64 (8x4 16x16 frags).
// LDS: 2 K-tile slots x (A 256x64 + B 256x64) bf16 = 128 KiB.
// Swizzle: 16B granule g of row r stored at g^(r&7); LDS dest linear,
// global source column pre-swizzled (global_load_lds stays direct).
// Pipelined schedule per K-tile u (slot su=u&1, sn=su^1):
//  p0: stage u+1c3 ; RD B(tile u, 8) + A-p1(4) ; lgkm(4) ; MFMA p0(afA,bC)
//  p1: stage u+2c0 ; RD A-p2(4)               ; lgkm(4) ; MFMA p1(afB,bC)
//  p2: stage u+2c1 ; RD A-p3(4)               ; lgkm(4) ; MFMA p2(afA,bC)
//  p3: stage u+2c2 ; vmcnt(6) ; barrier ; RD A-p0-next(4, slot sn) ;
//      lgkm(4) ; MFMA p3(afB,bC)
// Each phase ends with s_barrier. lgkm(4) = "all but the 4 reads just issued
// are done" -> the frags being consumed (issued last phase) have landed.
// Boundary vmcnt(6): tile u+1's chunks all older than the 3 newest chunks.
// MODE: 0 qkv +bias->bf16   1 scores *scale->bf16   2 pv plain->bf16
//       3 proj +bias+res(raw)->bf16   4 fc +bias,gelu->bf16
//       5 fc2 +bias+res(bf16)->flag dtype
// CAUSAL: 0 none (T1 XCD swizzle), 1 triangular tile enum, 2 K clamp to m0+256
template <int MODE, int CAUSAL>
__global__ __launch_bounds__(512, 2) void gemm_8ph(
        const u16* __restrict__ A, int lda, long aBatch,
        const u16* __restrict__ Bt, int ldb, long bBatch,
        const void* __restrict__ bias,
        void* __restrict__ Cv, int ldc, long cBatch,
        const void* __restrict__ res,
        float scale, const int* __restrict__ flagp, int K) {
    __shared__ __align__(16) u16 sA[2][256 * 64];   // 64 KiB
    __shared__ __align__(16) u16 sB[2][256 * 64];   // 64 KiB

    int m0, n0;
    if (CAUSAL == 1) {
        // enumerate lower-triangular 256^2 tiles: bx -> (ti, tj), tj <= ti
        const int bx = blockIdx.x;
        int ti = (int)((sqrtf(8.0f * bx + 1.0f) - 1.0f) * 0.5f);
        while ((ti + 1) * (ti + 2) / 2 <= bx) ++ti;
        while (ti * (ti + 1) / 2 > bx) --ti;
        m0 = ti * 256;
        n0 = (bx - ti * (ti + 1) / 2) * 256;
    } else if (CAUSAL == 2) {
        m0 = blockIdx.y * 256;
        n0 = blockIdx.x * 256;
    } else {
        // T1: bijective XCD chunk swizzle (launches have nwg % 8 == 0)
        const int gx  = gridDim.x;
        const int nwg = gx * gridDim.y;
        const int fid = blockIdx.y * gx + blockIdx.x;
        const int swz = (fid & 7) * (nwg >> 3) + (fid >> 3);
        m0 = (swz / gx) * 256;
        n0 = (swz % gx) * 256;
    }
    const int bz = blockIdx.z;
    A  += (long)bz * aBatch;
    Bt += (long)bz * bBatch;

    const int tid  = threadIdx.x;
    const int lane = tid & 63, wv = tid >> 6;
    const int wm = wv >> 2, wn = wv & 3;            // 2 x 4 wave grid
    const int l16 = lane & 15, quad = lane >> 4;
    const int xg = l16 & 7;                         // read-side granule XOR

    // staging mapping: 512 threads cover 64 rows x 8 granules, linear dest
    const int rq   = tid >> 3;                      // 0..63
    const int gsrc = ((tid & 7) ^ (rq & 7)) * 8;    // pre-swizzled source col
    const int gdst = (tid & 7) * 8;                 // linear dest granule
    const int rAb  = (rq < 32) ? rq : 96 + rq;      // A rows {0..31}|{128..159}

    int NT = K >> 6;
    if (CAUSAL == 2) NT = min(K, m0 + 256) >> 6;    // probs zero past t|255

#define STAGE8(t_, q_) do {                                                      \
        const int sl_ = (t_) & 1;                                                \
        const int k0_ = (t_) << 6;                                               \
        const int ra_ = ((q_) << 5) + rAb;                                       \
        GLOAD_LDS16(A + (long)(m0 + ra_) * lda + k0_ + gsrc,                     \
                    &sA[sl_][ra_ * 64 + gdst]);                                  \
        const int rb_ = ((q_) << 6) + rq;                                        \
        GLOAD_LDS16(Bt + (long)(n0 + rb_) * ldb + k0_ + gsrc,                    \
                    &sB[sl_][rb_ * 64 + gdst]);                                  \
    } while (0)

#define PBAR8() do { __builtin_amdgcn_sched_barrier(0);                          \
        asm volatile("s_barrier" ::: "memory");                                  \
        __builtin_amdgcn_sched_barrier(0); } while (0)

#define WVM8(n_) do { __builtin_amdgcn_sched_barrier(0);                         \
        asm volatile("s_waitcnt vmcnt(" #n_ ")" ::: "memory");                   \
        __builtin_amdgcn_sched_barrier(0); } while (0)

#define WLGKM(n_) do { __builtin_amdgcn_sched_barrier(0);                        \
        asm volatile("s_waitcnt lgkmcnt(" #n_ ")" ::: "memory");                 \
        __builtin_amdgcn_sched_barrier(0); } while (0)

    // A quadrant reads for phase qn_ (4x b128) into buf_[2][2]
#define RD_A(buf_, qn_, sl_) do {                                                \
        DSR128(buf_[0][0], &sA[sl_][(wm * 128 + (2 * (qn_) + 0) * 16 + l16) * 64 \
                                    + (((0 * 4 + quad) ^ xg) * 8)]);             \
        DSR128(buf_[0][1], &sA[sl_][(wm * 128 + (2 * (qn_) + 0) * 16 + l16) * 64 \
                                    + (((1 * 4 + quad) ^ xg) * 8)]);             \
        DSR128(buf_[1][0], &sA[sl_][(wm * 128 + (2 * (qn_) + 1) * 16 + l16) * 64 \
                                    + (((0 * 4 + quad) ^ xg) * 8)]);             \
        DSR128(buf_[1][1], &sA[sl_][(wm * 128 + (2 * (qn_) + 1) * 16 + l16) * 64 \
                                    + (((1 * 4 + quad) ^ xg) * 8)]);             \
    } while (0)

    // all 8 B frag reads for the tile in slot sl_
#define RD_B(sl_) do {                                                           \
        DSR128(bC[0][0], &sB[sl_][(wn * 64 + 0 * 16 + l16) * 64 + (((0 * 4 + quad) ^ xg) * 8)]); \
        DSR128(bC[0][1], &sB[sl_][(wn * 64 + 0 * 16 + l16) * 64 + (((1 * 4 + quad) ^ xg) * 8)]); \
        DSR128(bC[1][0], &sB[sl_][(wn * 64 + 1 * 16 + l16) * 64 + (((0 * 4 + quad) ^ xg) * 8)]); \
        DSR128(bC[1][1], &sB[sl_][(wn * 64 + 1 * 16 + l16) * 64 + (((1 * 4 + quad) ^ xg) * 8)]); \
        DSR128(bC[2][0], &sB[sl_][(wn * 64 + 2 * 16 + l16) * 64 + (((0 * 4 + quad) ^ xg) * 8)]); \
        DSR128(bC[2][1], &sB[sl_][(wn * 64 + 2 * 16 + l16) * 64 + (((1 * 4 + quad) ^ xg) * 8)]); \
        DSR128(bC[3][0], &sB[sl_][(wn * 64 + 3 * 16 + l16) * 64 + (((0 * 4 + quad) ^ xg) * 8)]); \
        DSR128(bC[3][1], &sB[sl_][(wn * 64 + 3 * 16 + l16) * 64 + (((1 * 4 + quad) ^ xg) * 8)]); \
    } while (0)

#define MFMA_PH(q_, A_) do {                                                     \
        __builtin_amdgcn_s_setprio(1);                                           \
        _Pragma("unroll")                                                        \
        for (int f_ = 0; f_ < 2; ++f_)                                           \
            _Pragma("unroll")                                                    \
            for (int j_ = 0; j_ < 4; ++j_) {                                     \
                acc[2 * (q_) + f_][j_] = __builtin_amdgcn_mfma_f32_16x16x32_bf16(\
                    A_[f_][0], bC[j_][0], acc[2 * (q_) + f_][j_], 0, 0, 0);      \
                acc[2 * (q_) + f_][j_] = __builtin_amdgcn_mfma_f32_16x16x32_bf16(\
                    A_[f_][1], bC[j_][1], acc[2 * (q_) + f_][j_], 0, 0, 0);      \
            }                                                                    \
        __builtin_amdgcn_s_setprio(0);                                           \
    } while (0)

    f32x4 acc[8][4];
    #pragma unroll
    for (int i = 0; i < 8; i++)
        #pragma unroll
        for (int j = 0; j < 4; j++) acc[i][j] = f32x4{0.f, 0.f, 0.f, 0.f};

    bf16x8 afA[2][2], afB[2][2], bC[4][2];

    // prologue: tile0 fully + tile1 chunks 0..2; tile0 landed (6 in flight);
    // prefetch A-p0 frags of tile 0.
    STAGE8(0, 0); STAGE8(0, 1); STAGE8(0, 2); STAGE8(0, 3);
    STAGE8(1, 0); STAGE8(1, 1); STAGE8(1, 2);
    WVM8(6);
    PBAR8();
    RD_A(afA, 0, 0);

    for (int u = 0; u < NT; ++u) {
        const int su = u & 1, sn = su ^ 1;
        // ---- p0: B(tile u) + A-p1 ------------------------------------
        if (u + 1 < NT) STAGE8(u + 1, 3);
        __builtin_amdgcn_sched_barrier(0);
        RD_B(su);
        RD_A(afB, 1, su);
        WLGKM(4);                       // afA (p3-issued) + bC landed
        MFMA_PH(0, afA);
        PBAR8();
        // ---- p1: A-p2 ------------------------------------------------
        if (u + 2 < NT) STAGE8(u + 2, 0);
        __builtin_amdgcn_sched_barrier(0);
        RD_A(afA, 2, su);
        WLGKM(4);                       // afB landed
        MFMA_PH(1, afB);
        PBAR8();
        // ---- p2: A-p3 ------------------------------------------------
        if (u + 2 < NT) STAGE8(u + 2, 1);
        __builtin_amdgcn_sched_barrier(0);
        RD_A(afB, 3, su);
        WLGKM(4);
        MFMA_PH(2, afA);
        PBAR8();
        // ---- p3: boundary + A-p0 of next tile ------------------------
        if (u + 2 < NT) { STAGE8(u + 2, 2); WVM8(6); } else { WVM8(0); }
        PBAR8();                        // tile u+1 visible to all waves
        RD_A(afA, 0, sn);
        WLGKM(4);
        MFMA_PH(3, afB);
        PBAR8();
    }
    WLGKM(0);                           // drain dead prefetch before reg reuse

    const int isbf = (MODE == 0 || MODE == 3 || MODE == 4 || MODE == 5) ? *flagp : 1;
    #pragma unroll
    for (int mi = 0; mi < 8; ++mi) {
        #pragma unroll
        for (int j = 0; j < 4; ++j) {
            #pragma unroll
            for (int r = 0; r < 4; ++r) {
                const int row = m0 + wm * 128 + mi * 16 + quad * 4 + r;
                const int col = n0 + wn * 64 + j * 16 + l16;
                const long idx = (long)bz * cBatch + (long)row * ldc + col;
                float v = acc[mi][j][r];
                if (MODE == 1) {
                    reinterpret_cast<u16*>(Cv)[idx] = f2bf(v * scale);
                } else if (MODE == 2) {
                    reinterpret_cast<u16*>(Cv)[idx] = f2bf(v);
                } else {
                    v += loadIn(bias, col, isbf);
                    if (MODE == 4) v = gelu_fast(v);
                    if (MODE == 3) v += loadIn(res, (long)row * ldc + col, isbf);
                    if (MODE == 5) v += bf2f(((const u16*)res)[(long)row * ldc + col]);
                    if (MODE == 5 && !isbf)
                        reinterpret_cast<float*>(Cv)[idx] = v;
                    else
                        reinterpret_cast<u16*>(Cv)[idx] = f2bf(v);
                }
            }
        }
    }
#undef STAGE8
#undef PBAR8
#undef WVM8
#undef WLGKM
#undef RD_A
#undef RD_B
#undef MFMA_PH
}

// ---------------- causal softmax: bf16 scores -> bf16 probs ----------------
// Row r: valid cols <= t=r&2047. PV (256-wide tiles, Keff = m0+256 clamp)
// reads cols < (t|255)+1, so zeros are stored out to t|255.
__global__ void softmax_causal(const u16* __restrict__ S, u16* __restrict__ P) {
    const long row = blockIdx.x;
    const int t = (int)(row & 2047);
    const u16* sr = S + row * 2048;
    u16* pr = P + row * 2048;
    const int tid = threadIdx.x;
    const int s0 = tid * 8;
    float v[8];
    float mx = -INFINITY;
    if (s0 <= t) {
        u16x8 raw = *reinterpret_cast<const u16x8*>(sr + s0);
        #pragma unroll
        for (int i = 0; i < 8; i++) {
            float x = bf2f(raw[i]);
            v[i] = (s0 + i <= t) ? x : -INFINITY;
            mx = fmaxf(mx, v[i]);
        }
    } else {
        #pragma unroll
        for (int i = 0; i < 8; i++) v[i] = -INFINITY;
    }
    mx = blockReduce<true>(mx);
    float sum = 0.f;
    #pragma unroll
    for (int i = 0; i < 8; i++) {
        float e = (v[i] == -INFINITY) ? 0.0f : __expf(v[i] - mx);
        v[i] = e;
        sum += e;
    }
    sum = blockReduce<false>(sum);
    float inv = 1.0f / sum;
    if (s0 <= (t | 255)) {
        u16x8 o;
        #pragma unroll
        for (int i = 0; i < 8; i++) o[i] = f2bf(v[i] * inv);
        *reinterpret_cast<u16x8*>(pr + s0) = o;
    }
}

// ---------------------------------------------------------------------------
extern "C" void kernel_launch(void* const* d_in, const int* in_sizes, int n_in,
                              void* d_out, int out_size, void* d_ws, size_t ws_size,
                              hipStream_t stream) {
    const void* x      = d_in[0];
    const void* w_attn = d_in[1];
    const void* b_attn = d_in[2];
    const void* w_proj = d_in[3];
    const void* b_proj = d_in[4];
    const void* ln1_g  = d_in[5];
    const void* ln1_b  = d_in[6];
    const void* ln2_g  = d_in[7];
    const void* ln2_b  = d_in[8];
    const void* w_fc   = d_in[9];
    const void* b_fc   = d_in[10];
    const void* w_fc2  = d_in[11];
    const void* b_fc2  = d_in[12];

    // workspace layout (176.16 MB + flag)
    char* ws = (char*)d_ws;
    u16*   hbuf   = (u16*)(ws);                      // 16.78 MB: h -> y -> h2
    u16*   qkv    = (u16*)(ws + 16777216);           // 50.33 MB (later: probs+x1)
    u16*   S      = (u16*)(ws + 67108864);           // 64 MB scores (later: g1)
    u16*   wattnT = (u16*)(ws + 134217728);          // 25.17 MB of w^T
    u16*   wprojT = wattnT + 3072 * 1024;
    u16*   wfcT   = wprojT + 1024 * 1024;
    u16*   wfc2T  = wfcT + 4096 * 1024;
    u16*   vT     = wfc2T + 1024 * 4096;             // 16.78 MB
    int*   flag   = (int*)(ws + 176160768);
    u16*   probs  = qkv;                   // reuses qkv region after scores
    u16*   x1     = qkv + 16777216;

    detect_dtype<<<1, 256, 0, stream>>>((const u16*)x, flag);

    // weight transposes (raw dtype -> bf16)
    transpose_to_bf16<<<dim3(96, 32, 1),  256, 0, stream>>>(w_attn, 3072, 0, wattnT, 1024, 0, flag);
    transpose_to_bf16<<<dim3(32, 32, 1),  256, 0, stream>>>(w_proj, 1024, 0, wprojT, 1024, 0, flag);
    transpose_to_bf16<<<dim3(128, 32, 1), 256, 0, stream>>>(w_fc,   4096, 0, wfcT,   1024, 0, flag);
    transpose_to_bf16<<<dim3(32, 128, 1), 256, 0, stream>>>(w_fc2,  1024, 0, wfc2T,  4096, 0, flag);

    // h = LN1(x)
    ln_kernel<true><<<8192, 256, 0, stream>>>(x, ln1_g, ln1_b, hbuf, flag);

    // qkv = h @ w_attn + b_attn       [8192, 3072]
    gemm_8ph<0, 0><<<dim3(12, 32, 1), 512, 0, stream>>>(
        hbuf, 1024, 0, wattnT, 1024, 0, b_attn, qkv, 3072, 0, nullptr, 0.f, flag, 1024);

    // vT[b] = V[b]^T                   [1024, 2048] x4
    transpose_to_bf16<<<dim3(32, 64, 4), 256, 0, stream>>>(
        qkv + 2048, 3072, (long)2048 * 3072, vT, 2048, (long)1024 * 2048, nullptr);

    // S[b] = 0.125 * q[b] @ k[b]^T    lower-tri 256^2 tiles (36 per batch)
    gemm_8ph<1, 1><<<dim3(36, 1, 4), 512, 0, stream>>>(
        qkv, 3072, (long)2048 * 3072, qkv + 1024, 3072, (long)2048 * 3072,
        nullptr, S, 2048, (long)2048 * 2048, nullptr, 0.125f, flag, 1024);

    // probs = causal softmax(S)  (stores zeros out to t|255)
    softmax_causal<<<8192, 256, 0, stream>>>(S, probs);

    // y[b] = P[b] @ V[b]              [2048, 1024] x4, K clamped to m0+256
    gemm_8ph<2, 2><<<dim3(4, 8, 4), 512, 0, stream>>>(
        probs, 2048, (long)2048 * 2048, vT, 2048, (long)1024 * 2048,
        nullptr, hbuf, 1024, (long)2048 * 1024, nullptr, 0.f, flag, 2048);

    // x1 = x + y @ w_proj + b_proj    (bf16, in ws)
    gemm_8ph<3, 0><<<dim3(4, 32, 1), 512, 0, stream>>>(
        hbuf, 1024, 0, wprojT, 1024, 0, b_proj, x1, 1024, 0, x, 0.f, flag, 1024);

    // h2 = LN2(x1) -> hbuf
    ln_kernel<false><<<8192, 256, 0, stream>>>(x1, ln2_g, ln2_b, hbuf, flag);

    // g1 = gelu(h2 @ w_fc + b_fc)     [8192, 4096] bf16 in S region
    gemm_8ph<4, 0><<<dim3(16, 32, 1), 512, 0, stream>>>(
        hbuf, 1024, 0, wfcT, 1024, 0, b_fc, S, 4096, 0, nullptr, 0.f, flag, 1024);

    // out = x1 + g1 @ w_fc2 + b_fc2   (written in detected dtype)
    gemm_8ph<5, 0><<<dim3(4, 32, 1), 512, 0, stream>>>(
        S, 4096, 0, wfc2T, 4096, 0, b_fc2, d_out, 1024, 0, x1, 0.f, flag, 4096);
}

// Round 4
// 665.780 us; speedup vs baseline: 1.0310x; 1.0310x over previous
//
#include <hip/hip_runtime.h>
#include <math.h>

// ---------------------------------------------------------------------------
// GPT transformer block, internal bf16 compute / fp32 accumulate.
// B=4, T=2048, D=1024 (8192 rows), 3D=3072, 4D=4096.
// Round 10: barrier-free tile interior. r8/r9 counters showed DS and MFMA
// pipes strictly alternating (tile = DS 2300 + MFMA 2483 + barriers = 4996
// cyc): per-phase s_barrier lockstep released/stalled all 8 waves together.
// Now: one staging burst at tile top (slot sn, never read this tile), 8
// barrier-free micro-phases (8 MFMA each, snake (mq,jp) order) with frag
// reads one phase ahead under counted lgkm, and a single
// barrier+vmcnt(0)+barrier at the tile boundary. At ~3000 cyc/tile the
// depth-1 staging (issued tile-top) lands long before the drain -> drain
// ~free. Race-free: slot sn is written only after every wave's reads of its
// old contents completed (lgkm(0) precedes barrier #1 in each wave).
// ---------------------------------------------------------------------------

typedef unsigned short u16;
typedef __attribute__((ext_vector_type(8))) short bf16x8;   // 8 bf16 = 4 VGPRs
typedef __attribute__((ext_vector_type(8))) unsigned short u16x8;
typedef __attribute__((ext_vector_type(4))) float f32x4;

#define DEV __device__ __forceinline__

#define GLOAD_LDS16(gp, lp)                                                     \
    __builtin_amdgcn_global_load_lds(                                           \
        (const __attribute__((address_space(1))) void*)(gp),                    \
        (__attribute__((address_space(3))) void*)(lp), 16, 0, 0)

// inline-asm LDS b128 read: invisible to SIInsertWaitcnts; pair with explicit
// counted s_waitcnt lgkmcnt + sched_barrier(0) before use (rule #18).
#define DSR128(dst_, p_)                                                        \
    asm volatile("ds_read_b128 %0, %1"                                          \
                 : "=v"(dst_)                                                   \
                 : "v"((unsigned)(unsigned long long)                           \
                       (__attribute__((address_space(3))) const void*)(p_)))

DEV float bf2f(u16 h) {
    union { unsigned u; float f; } t; t.u = ((unsigned)h) << 16; return t.f;
}
DEV u16 f2bf(float f) {
    union { unsigned u; float f; } t; t.f = f;
    unsigned u = t.u;
    return (u16)((u + 0x7FFFu + ((u >> 16) & 1u)) >> 16);   // round-nearest-even
}
DEV float loadIn(const void* p, long i, int isbf) {
    return isbf ? bf2f(((const u16*)p)[i]) : ((const float*)p)[i];
}
// gelu(x) = 0.5x(1+tanh(u)) = x * sigmoid(2u)
DEV float gelu_fast(float x) {
    float u = 1.5957691216057308f * (x + 0.044715f * x * x * x);  // 2*sqrt(2/pi)
    return x * __builtin_amdgcn_rcpf(1.0f + __expf(-u));
}

DEV float waveSum(float v) {
    #pragma unroll
    for (int o = 32; o > 0; o >>= 1) v += __shfl_down(v, o, 64);
    return v;
}
DEV float waveMax(float v) {
    #pragma unroll
    for (int o = 32; o > 0; o >>= 1) v = fmaxf(v, __shfl_down(v, o, 64));
    return v;
}

template <bool IS_MAX>
DEV float blockReduce(float v) {
    __shared__ float tmp[5];
    __syncthreads();
    v = IS_MAX ? waveMax(v) : waveSum(v);
    int lane = threadIdx.x & 63, w = threadIdx.x >> 6;
    if (lane == 0) tmp[w] = v;
    __syncthreads();
    if (threadIdx.x == 0) {
        float r = tmp[0];
        for (int i = 1; i < 4; i++) r = IS_MAX ? fmaxf(r, tmp[i]) : (r + tmp[i]);
        tmp[4] = r;
    }
    __syncthreads();
    return tmp[4];
}

// ---------------- dtype detection (1 block) --------------------------------
__global__ void detect_dtype(const u16* __restrict__ xr, int* __restrict__ flag) {
    const int tid = threadIdx.x;           // 256
    int cnt = 0;
    #pragma unroll
    for (int i = 0; i < 16; i++) {
        unsigned u = xr[2 * (tid + 256 * i)];      // even u16 indices
        unsigned e = (u >> 7) & 0xFF;              // bf16 exponent field
        cnt += (e >= 100 && e <= 140) ? 1 : 0;     // ~always for bf16 N(0,1)
    }
    __shared__ int sh[4];
    #pragma unroll
    for (int o = 32; o > 0; o >>= 1) cnt += __shfl_down(cnt, o, 64);
    if ((tid & 63) == 0) sh[tid >> 6] = cnt;
    __syncthreads();
    if (tid == 0) flag[0] = (sh[0] + sh[1] + sh[2] + sh[3] > 2048) ? 1 : 0;
}

// ---------------- LayerNorm (D=1024, one 256-thread block per row) ---------
template <bool RAW_IN>
__global__ void ln_kernel(const void* __restrict__ x, const void* __restrict__ g,
                          const void* __restrict__ b, u16* __restrict__ out,
                          const int* __restrict__ flagp) {
    const int isbf = *flagp;
    const int inbf = RAW_IN ? isbf : 1;
    const long base = (long)blockIdx.x * 1024;
    const int tid = threadIdx.x;
    float v[4];
    #pragma unroll
    for (int j = 0; j < 4; j++) v[j] = loadIn(x, base + tid + 256 * j, inbf);
    float mu = blockReduce<false>(v[0] + v[1] + v[2] + v[3]) * (1.0f / 1024.0f);
    float d[4], sq = 0.f;
    #pragma unroll
    for (int j = 0; j < 4; j++) { d[j] = v[j] - mu; sq += d[j] * d[j]; }
    float var = blockReduce<false>(sq) * (1.0f / 1024.0f);
    float rstd = rsqrtf(var + 1e-5f);
    #pragma unroll
    for (int j = 0; j < 4; j++) {
        int c = tid + 256 * j;
        out[base + c] = f2bf(d[j] * rstd * loadIn(g, c, isbf) + loadIn(b, c, isbf));
    }
}

// ---------------- 32x32 transpose -> bf16 ----------------------------------
__global__ void transpose_to_bf16(const void* __restrict__ in, int ldin, long inBatch,
                                  u16* __restrict__ out, int ldout, long outBatch,
                                  const int* __restrict__ flagp) {
    __shared__ u16 tile[32][33];
    const int isbf = flagp ? *flagp : 1;
    const long ibase = (long)blockIdx.z * inBatch;
    out += (long)blockIdx.z * outBatch;
    const int bc = blockIdx.x * 32, br = blockIdx.y * 32;
    const int tx = threadIdx.x & 31, ty = threadIdx.x >> 5;   // 256 thr
    #pragma unroll
    for (int i = 0; i < 32; i += 8)
        tile[ty + i][tx] = f2bf(loadIn(in, ibase + (long)(br + ty + i) * ldin + bc + tx, isbf));
    __syncthreads();
    #pragma unroll
    for (int i = 0; i < 32; i += 8)
        out[(long)(bc + ty + i) * ldout + br + tx] = tile[tx][ty + i];
}

// ---------------- 256x256 barrier-free-interior GEMM -----------------------
// C[M,N] = A[M,K] @ (Bt[N,K])^T (+epilogue). M%256==0, N%256==0, K%64==0.
// 512 threads = 8 waves (2M x 4N), per-wave C tile 128x64 (8x4 16x16 frags).
// LDS: 2 K-tile slots x (A 256x64 + B 256x64) bf16 = 128 KiB.
// Swizzle: 16B granule g of row r stored at g^(r&7); LDS dest linear,
// global source column pre-swizzled (global_load_lds stays direct).
// Per K-tile u (slot su): stage ALL of tile u+1 -> slot sn at tile top;
// 8 barrier-free micro-phases of 8 MFMA, snake (mq,jp) order
// (0,0)(0,1)(1,1)(1,0)(2,0)(2,1)(3,1)(3,0); A quads double-buffered
// (afA/afB), B halves bJ0 (j0,j1) / bJ1 (j2,j3) live whole tile; frag reads
// one phase ahead, counted lgkm. Boundary: barrier; vmcnt(0); barrier; then
// prefetch next tile's A-q0 + bJ0 from sn.
// MODE: 0 qkv +bias->bf16   1 scores *scale->bf16   2 pv plain->bf16
//       3 proj +bias+res(raw)->bf16   4 fc +bias,gelu->bf16
//       5 fc2 +bias+res(bf16)->flag dtype
// CAUSAL: 0 none (T1 XCD swizzle), 1 triangular tile enum, 2 K clamp to m0+256
template <int MODE, int CAUSAL>
__global__ __launch_bounds__(512, 2) void gemm_8ph(
        const u16* __restrict__ A, int lda, long aBatch,
        const u16* __restrict__ Bt, int ldb, long bBatch,
        const void* __restrict__ bias,
        void* __restrict__ Cv, int ldc, long cBatch,
        const void* __restrict__ res,
        float scale, const int* __restrict__ flagp, int K) {
    __shared__ __align__(16) u16 sA[2][256 * 64];   // 64 KiB
    __shared__ __align__(16) u16 sB[2][256 * 64];   // 64 KiB

    int m0, n0;
    if (CAUSAL == 1) {
        // enumerate lower-triangular 256^2 tiles: bx -> (ti, tj), tj <= ti
        const int bx = blockIdx.x;
        int ti = (int)((sqrtf(8.0f * bx + 1.0f) - 1.0f) * 0.5f);
        while ((ti + 1) * (ti + 2) / 2 <= bx) ++ti;
        while (ti * (ti + 1) / 2 > bx) --ti;
        m0 = ti * 256;
        n0 = (bx - ti * (ti + 1) / 2) * 256;
    } else if (CAUSAL == 2) {
        m0 = (gridDim.y - 1 - blockIdx.y) * 256;   // big-NT blocks dispatch first
        n0 = blockIdx.x * 256;
    } else {
        // T1: bijective XCD chunk swizzle (launches have nwg % 8 == 0)
        const int gx  = gridDim.x;
        const int nwg = gx * gridDim.y;
        const int fid = blockIdx.y * gx + blockIdx.x;
        const int swz = (fid & 7) * (nwg >> 3) + (fid >> 3);
        m0 = (swz / gx) * 256;
        n0 = (swz % gx) * 256;
    }
    const int bz = blockIdx.z;
    A  += (long)bz * aBatch;
    Bt += (long)bz * bBatch;

    const int tid  = threadIdx.x;
    const int lane = tid & 63, wv = tid >> 6;
    const int wm = wv >> 2, wn = wv & 3;            // 2 x 4 wave grid
    const int l16 = lane & 15, quad = lane >> 4;
    const int xg = l16 & 7;                         // read-side granule XOR

    // staging mapping: 512 threads cover 64 rows x 8 granules, linear dest
    const int rq   = tid >> 3;                      // 0..63
    const int gsrc = ((tid & 7) ^ (rq & 7)) * 8;    // pre-swizzled source col
    const int gdst = (tid & 7) * 8;                 // linear dest granule
    const int rAb  = (rq < 32) ? rq : 96 + rq;      // A rows {0..31}|{128..159}

    int NT = K >> 6;
    if (CAUSAL == 2) NT = min(K, m0 + 256) >> 6;    // probs zero past t|255

#define STAGE8(t_, q_) do {                                                      \
        const int sl_ = (t_) & 1;                                                \
        const int k0_ = (t_) << 6;                                               \
        const int ra_ = ((q_) << 5) + rAb;                                       \
        GLOAD_LDS16(A + (long)(m0 + ra_) * lda + k0_ + gsrc,                     \
                    &sA[sl_][ra_ * 64 + gdst]);                                  \
        const int rb_ = ((q_) << 6) + rq;                                        \
        GLOAD_LDS16(Bt + (long)(n0 + rb_) * ldb + k0_ + gsrc,                    \
                    &sB[sl_][rb_ * 64 + gdst]);                                  \
    } while (0)

#define BAR8() asm volatile("s_barrier" ::: "memory")

#define WVMC(n_) do {                                                            \
        asm volatile("s_waitcnt vmcnt(" #n_ ")" ::: "memory");                   \
        __builtin_amdgcn_sched_barrier(0); } while (0)

#define WLGKM(n_) do {                                                           \
        asm volatile("s_waitcnt lgkmcnt(" #n_ ")" ::: "memory");                 \
        __builtin_amdgcn_sched_barrier(0); } while (0)

    // A quadrant reads for quad qn_ (4x b128) into buf_[2][2]
#define RD_A4(buf_, qn_, sl_) do {                                               \
        DSR128(buf_[0][0], &sA[sl_][(wm * 128 + (2 * (qn_) + 0) * 16 + l16) * 64 \
                                    + (((0 * 4 + quad) ^ xg) * 8)]);             \
        DSR128(buf_[0][1], &sA[sl_][(wm * 128 + (2 * (qn_) + 0) * 16 + l16) * 64 \
                                    + (((1 * 4 + quad) ^ xg) * 8)]);             \
        DSR128(buf_[1][0], &sA[sl_][(wm * 128 + (2 * (qn_) + 1) * 16 + l16) * 64 \
                                    + (((0 * 4 + quad) ^ xg) * 8)]);             \
        DSR128(buf_[1][1], &sA[sl_][(wm * 128 + (2 * (qn_) + 1) * 16 + l16) * 64 \
                                    + (((1 * 4 + quad) ^ xg) * 8)]);             \
    } while (0)

    // B half jp_ (j = 2*jp_, 2*jp_+1): 4x b128 into buf_[2][2]
#define RD_B4(buf_, jp_, sl_) do {                                               \
        DSR128(buf_[0][0], &sB[sl_][(wn * 64 + (2 * (jp_) + 0) * 16 + l16) * 64  \
                                    + (((0 * 4 + quad) ^ xg) * 8)]);             \
        DSR128(buf_[0][1], &sB[sl_][(wn * 64 + (2 * (jp_) + 0) * 16 + l16) * 64  \
                                    + (((1 * 4 + quad) ^ xg) * 8)]);             \
        DSR128(buf_[1][0], &sB[sl_][(wn * 64 + (2 * (jp_) + 1) * 16 + l16) * 64  \
                                    + (((0 * 4 + quad) ^ xg) * 8)]);             \
        DSR128(buf_[1][1], &sB[sl_][(wn * 64 + (2 * (jp_) + 1) * 16 + l16) * 64  \
                                    + (((1 * 4 + quad) ^ xg) * 8)]);             \
    } while (0)

    // 8 MFMA: acc[2*mq_+f][2*jp_+jj] += A_[f][s] * B_[jj][s]
#define MFMA8(mq_, jp_, A_, B_) do {                                             \
        _Pragma("unroll")                                                        \
        for (int f_ = 0; f_ < 2; ++f_)                                           \
            _Pragma("unroll")                                                    \
            for (int jj_ = 0; jj_ < 2; ++jj_) {                                  \
                acc[2 * (mq_) + f_][2 * (jp_) + jj_] =                           \
                    __builtin_amdgcn_mfma_f32_16x16x32_bf16(                     \
                        A_[f_][0], B_[jj_][0],                                   \
                        acc[2 * (mq_) + f_][2 * (jp_) + jj_], 0, 0, 0);          \
                acc[2 * (mq_) + f_][2 * (jp_) + jj_] =                           \
                    __builtin_amdgcn_mfma_f32_16x16x32_bf16(                     \
                        A_[f_][1], B_[jj_][1],                                   \
                        acc[2 * (mq_) + f_][2 * (jp_) + jj_], 0, 0, 0);          \
            }                                                                    \
    } while (0)

    f32x4 acc[8][4];
    #pragma unroll
    for (int i = 0; i < 8; i++)
        #pragma unroll
        for (int j = 0; j < 4; j++) acc[i][j] = f32x4{0.f, 0.f, 0.f, 0.f};

    bf16x8 afA[2][2], afB[2][2], bJ0[2][2], bJ1[2][2];

    // prologue: stage tile 0 into slot 0; confirm; prefetch A-q0 + B-half0.
    STAGE8(0, 0); STAGE8(0, 1); STAGE8(0, 2); STAGE8(0, 3);
    WVMC(0);
    BAR8();
    RD_A4(afA, 0, 0);
    RD_B4(bJ0, 0, 0);

    for (int u = 0; u < NT; ++u) {
        const int su = u & 1, sn = su ^ 1;
        // tile top: stage ALL of tile u+1 into slot sn (never read this tile)
        if (u + 1 < NT) { STAGE8(u + 1, 0); STAGE8(u + 1, 1);
                          STAGE8(u + 1, 2); STAGE8(u + 1, 3); }
        // ph0 (mq0,jp0): issue B-half1; wait prefetched afA+bJ0
        RD_B4(bJ1, 1, su);
        WLGKM(4); MFMA8(0, 0, afA, bJ0);
        // ph1 (mq0,jp1): issue A-q1; wait bJ1
        RD_A4(afB, 1, su);
        WLGKM(4); MFMA8(0, 1, afA, bJ1);
        // ph2 (mq1,jp1): wait afB
        WLGKM(0); MFMA8(1, 1, afB, bJ1);
        // ph3 (mq1,jp0): issue A-q2
        RD_A4(afA, 2, su);
        WLGKM(4); MFMA8(1, 0, afB, bJ0);
        // ph4 (mq2,jp0): wait afA(q2)
        WLGKM(0); MFMA8(2, 0, afA, bJ0);
        // ph5 (mq2,jp1): issue A-q3
        RD_A4(afB, 3, su);
        WLGKM(4); MFMA8(2, 1, afA, bJ1);
        // ph6 (mq3,jp1): wait afB(q3)
        WLGKM(0); MFMA8(3, 1, afB, bJ1);
        // ph7 (mq3,jp0): frags already landed
        MFMA8(3, 0, afB, bJ0);
        // boundary: all waves' reads of sn's old data are done (each wave's
        // lgkm(0) preceded its barrier arrival) -> safe to expose staging.
        BAR8();
        WVMC(0);                       // own tile-top stages landed (~free)
        BAR8();                        // everyone's landed
        if (u + 1 < NT) {              // prefetch next tile's first frags
            RD_A4(afA, 0, sn);
            RD_B4(bJ0, 0, sn);
        }
    }
    WLGKM(0);                          // quiesce before frag-reg reuse

    const int isbf = (MODE == 0 || MODE == 3 || MODE == 4 || MODE == 5) ? *flagp : 1;
    #pragma unroll
    for (int mi = 0; mi < 8; ++mi) {
        #pragma unroll
        for (int j = 0; j < 4; ++j) {
            #pragma unroll
            for (int r = 0; r < 4; ++r) {
                const int row = m0 + wm * 128 + mi * 16 + quad * 4 + r;
                const int col = n0 + wn * 64 + j * 16 + l16;
                const long idx = (long)bz * cBatch + (long)row * ldc + col;
                float v = acc[mi][j][r];
                if (MODE == 1) {
                    reinterpret_cast<u16*>(Cv)[idx] = f2bf(v * scale);
                } else if (MODE == 2) {
                    reinterpret_cast<u16*>(Cv)[idx] = f2bf(v);
                } else {
                    v += loadIn(bias, col, isbf);
                    if (MODE == 4) v = gelu_fast(v);
                    if (MODE == 3) v += loadIn(res, (long)row * ldc + col, isbf);
                    if (MODE == 5) v += bf2f(((const u16*)res)[(long)row * ldc + col]);
                    if (MODE == 5 && !isbf)
                        reinterpret_cast<float*>(Cv)[idx] = v;
                    else
                        reinterpret_cast<u16*>(Cv)[idx] = f2bf(v);
                }
            }
        }
    }
#undef STAGE8
#undef BAR8
#undef WVMC
#undef WLGKM
#undef RD_A4
#undef RD_B4
#undef MFMA8
}

// ---------------- causal softmax: bf16 scores -> bf16 probs ----------------
// Row r: valid cols <= t=r&2047. PV (256-wide tiles, Keff = m0+256 clamp)
// reads cols < (t|255)+1, so zeros are stored out to t|255.
__global__ void softmax_causal(const u16* __restrict__ S, u16* __restrict__ P) {
    const long row = blockIdx.x;
    const int t = (int)(row & 2047);
    const u16* sr = S + row * 2048;
    u16* pr = P + row * 2048;
    const int tid = threadIdx.x;
    const int s0 = tid * 8;
    float v[8];
    float mx = -INFINITY;
    if (s0 <= t) {
        u16x8 raw = *reinterpret_cast<const u16x8*>(sr + s0);
        #pragma unroll
        for (int i = 0; i < 8; i++) {
            float x = bf2f(raw[i]);
            v[i] = (s0 + i <= t) ? x : -INFINITY;
            mx = fmaxf(mx, v[i]);
        }
    } else {
        #pragma unroll
        for (int i = 0; i < 8; i++) v[i] = -INFINITY;
    }
    mx = blockReduce<true>(mx);
    float sum = 0.f;
    #pragma unroll
    for (int i = 0; i < 8; i++) {
        float e = (v[i] == -INFINITY) ? 0.0f : __expf(v[i] - mx);
        v[i] = e;
        sum += e;
    }
    sum = blockReduce<false>(sum);
    float inv = 1.0f / sum;
    if (s0 <= (t | 255)) {
        u16x8 o;
        #pragma unroll
        for (int i = 0; i < 8; i++) o[i] = f2bf(v[i] * inv);
        *reinterpret_cast<u16x8*>(pr + s0) = o;
    }
}

// ---------------------------------------------------------------------------
extern "C" void kernel_launch(void* const* d_in, const int* in_sizes, int n_in,
                              void* d_out, int out_size, void* d_ws, size_t ws_size,
                              hipStream_t stream) {
    const void* x      = d_in[0];
    const void* w_attn = d_in[1];
    const void* b_attn = d_in[2];
    const void* w_proj = d_in[3];
    const void* b_proj = d_in[4];
    const void* ln1_g  = d_in[5];
    const void* ln1_b  = d_in[6];
    const void* ln2_g  = d_in[7];
    const void* ln2_b  = d_in[8];
    const void* w_fc   = d_in[9];
    const void* b_fc   = d_in[10];
    const void* w_fc2  = d_in[11];
    const void* b_fc2  = d_in[12];

    // workspace layout (176.16 MB + flag)
    char* ws = (char*)d_ws;
    u16*   hbuf   = (u16*)(ws);                      // 16.78 MB: h -> y -> h2
    u16*   qkv    = (u16*)(ws + 16777216);           // 50.33 MB (later: probs+x1)
    u16*   S      = (u16*)(ws + 67108864);           // 64 MB scores (later: g1)
    u16*   wattnT = (u16*)(ws + 134217728);          // 25.17 MB of w^T
    u16*   wprojT = wattnT + 3072 * 1024;
    u16*   wfcT   = wprojT + 1024 * 1024;
    u16*   wfc2T  = wfcT + 4096 * 1024;
    u16*   vT     = wfc2T + 1024 * 4096;             // 16.78 MB
    int*   flag   = (int*)(ws + 176160768);
    u16*   probs  = qkv;                   // reuses qkv region after scores
    u16*   x1     = qkv + 16777216;

    detect_dtype<<<1, 256, 0, stream>>>((const u16*)x, flag);

    // weight transposes (raw dtype -> bf16)
    transpose_to_bf16<<<dim3(96, 32, 1),  256, 0, stream>>>(w_attn, 3072, 0, wattnT, 1024, 0, flag);
    transpose_to_bf16<<<dim3(32, 32, 1),  256, 0, stream>>>(w_proj, 1024, 0, wprojT, 1024, 0, flag);
    transpose_to_bf16<<<dim3(128, 32, 1), 256, 0, stream>>>(w_fc,   4096, 0, wfcT,   1024, 0, flag);
    transpose_to_bf16<<<dim3(32, 128, 1), 256, 0, stream>>>(w_fc2,  1024, 0, wfc2T,  4096, 0, flag);

    // h = LN1(x)
    ln_kernel<true><<<8192, 256, 0, stream>>>(x, ln1_g, ln1_b, hbuf, flag);

    // qkv = h @ w_attn + b_attn       [8192, 3072]
    gemm_8ph<0, 0><<<dim3(12, 32, 1), 512, 0, stream>>>(
        hbuf, 1024, 0, wattnT, 1024, 0, b_attn, qkv, 3072, 0, nullptr, 0.f, flag, 1024);

    // vT[b] = V[b]^T                   [1024, 2048] x4
    transpose_to_bf16<<<dim3(32, 64, 4), 256, 0, stream>>>(
        qkv + 2048, 3072, (long)2048 * 3072, vT, 2048, (long)1024 * 2048, nullptr);

    // S[b] = 0.125 * q[b] @ k[b]^T    lower-tri 256^2 tiles (36 per batch)
    gemm_8ph<1, 1><<<dim3(36, 1, 4), 512, 0, stream>>>(
        qkv, 3072, (long)2048 * 3072, qkv + 1024, 3072, (long)2048 * 3072,
        nullptr, S, 2048, (long)2048 * 2048, nullptr, 0.125f, flag, 1024);

    // probs = causal softmax(S)  (stores zeros out to t|255)
    softmax_causal<<<8192, 256, 0, stream>>>(S, probs);

    // y[b] = P[b] @ V[b]              [2048, 1024] x4, K clamped to m0+256
    gemm_8ph<2, 2><<<dim3(4, 8, 4), 512, 0, stream>>>(
        probs, 2048, (long)2048 * 2048, vT, 2048, (long)1024 * 2048,
        nullptr, hbuf, 1024, (long)2048 * 1024, nullptr, 0.f, flag, 2048);

    // x1 = x + y @ w_proj + b_proj    (bf16, in ws)
    gemm_8ph<3, 0><<<dim3(4, 32, 1), 512, 0, stream>>>(
        hbuf, 1024, 0, wprojT, 1024, 0, b_proj, x1, 1024, 0, x, 0.f, flag, 1024);

    // h2 = LN2(x1) -> hbuf
    ln_kernel<false><<<8192, 256, 0, stream>>>(x1, ln2_g, ln2_b, hbuf, flag);

    // g1 = gelu(h2 @ w_fc + b_fc)     [8192, 4096] bf16 in S region
    gemm_8ph<4, 0><<<dim3(16, 32, 1), 512, 0, stream>>>(
        hbuf, 1024, 0, wfcT, 1024, 0, b_fc, S, 4096, 0, nullptr, 0.f, flag, 1024);

    // out = x1 + g1 @ w_fc2 + b_fc2   (written in detected dtype)
    gemm_8ph<5, 0><<<dim3(4, 32, 1), 512, 0, stream>>>(
        S, 4096, 0, wfc2T, 4096, 0, b_fc2, d_out, 1024, 0, x1, 0.f, flag, 4096);
}

// Round 5
// 577.395 us; speedup vs baseline: 1.1889x; 1.1531x over previous
//
#include <hip/hip_runtime.h>
#include <math.h>

// ---------------------------------------------------------------------------
// GPT transformer block, internal bf16 compute / fp32 accumulate.
// B=4, T=2048, D=1024 (8192 rows), 3D=3072, 4D=4096.
// Round 11: grid starvation fix. fc2/proj/pv ran 128 blocks on 256 CUs (half
// the chip idle, Occupancy 11%). New BM=128 x BN=256 tile variant (96 KiB
// LDS) doubles their grids to 256 blocks. BM=256 path is r10's passing code.
// Also: setprio(1) around MFMA clusters (T5), and MFMA clusters issue the 4
// independent s=0 ops before the dependent s=1 ops (dep distance 1 -> 4).
// r7-r10 lesson: schedule micro-variants all land at the no-overlap DS+MFMA
// sum (~4800 cyc/tile); stop tuning choreography, feed the chip instead.
// ---------------------------------------------------------------------------

typedef unsigned short u16;
typedef __attribute__((ext_vector_type(8))) short bf16x8;   // 8 bf16 = 4 VGPRs
typedef __attribute__((ext_vector_type(8))) unsigned short u16x8;
typedef __attribute__((ext_vector_type(4))) float f32x4;

#define DEV __device__ __forceinline__

#define GLOAD_LDS16(gp, lp)                                                     \
    __builtin_amdgcn_global_load_lds(                                           \
        (const __attribute__((address_space(1))) void*)(gp),                    \
        (__attribute__((address_space(3))) void*)(lp), 16, 0, 0)

// inline-asm LDS b128 read: invisible to SIInsertWaitcnts; pair with explicit
// counted s_waitcnt lgkmcnt + sched_barrier(0) before use (rule #18).
#define DSR128(dst_, p_)                                                        \
    asm volatile("ds_read_b128 %0, %1"                                          \
                 : "=v"(dst_)                                                   \
                 : "v"((unsigned)(unsigned long long)                           \
                       (__attribute__((address_space(3))) const void*)(p_)))

DEV float bf2f(u16 h) {
    union { unsigned u; float f; } t; t.u = ((unsigned)h) << 16; return t.f;
}
DEV u16 f2bf(float f) {
    union { unsigned u; float f; } t; t.f = f;
    unsigned u = t.u;
    return (u16)((u + 0x7FFFu + ((u >> 16) & 1u)) >> 16);   // round-nearest-even
}
DEV float loadIn(const void* p, long i, int isbf) {
    return isbf ? bf2f(((const u16*)p)[i]) : ((const float*)p)[i];
}
// gelu(x) = 0.5x(1+tanh(u)) = x * sigmoid(2u)
DEV float gelu_fast(float x) {
    float u = 1.5957691216057308f * (x + 0.044715f * x * x * x);  // 2*sqrt(2/pi)
    return x * __builtin_amdgcn_rcpf(1.0f + __expf(-u));
}

DEV float waveSum(float v) {
    #pragma unroll
    for (int o = 32; o > 0; o >>= 1) v += __shfl_down(v, o, 64);
    return v;
}
DEV float waveMax(float v) {
    #pragma unroll
    for (int o = 32; o > 0; o >>= 1) v = fmaxf(v, __shfl_down(v, o, 64));
    return v;
}

template <bool IS_MAX>
DEV float blockReduce(float v) {
    __shared__ float tmp[5];
    __syncthreads();
    v = IS_MAX ? waveMax(v) : waveSum(v);
    int lane = threadIdx.x & 63, w = threadIdx.x >> 6;
    if (lane == 0) tmp[w] = v;
    __syncthreads();
    if (threadIdx.x == 0) {
        float r = tmp[0];
        for (int i = 1; i < 4; i++) r = IS_MAX ? fmaxf(r, tmp[i]) : (r + tmp[i]);
        tmp[4] = r;
    }
    __syncthreads();
    return tmp[4];
}

// ---------------- dtype detection (1 block) --------------------------------
__global__ void detect_dtype(const u16* __restrict__ xr, int* __restrict__ flag) {
    const int tid = threadIdx.x;           // 256
    int cnt = 0;
    #pragma unroll
    for (int i = 0; i < 16; i++) {
        unsigned u = xr[2 * (tid + 256 * i)];      // even u16 indices
        unsigned e = (u >> 7) & 0xFF;              // bf16 exponent field
        cnt += (e >= 100 && e <= 140) ? 1 : 0;     // ~always for bf16 N(0,1)
    }
    __shared__ int sh[4];
    #pragma unroll
    for (int o = 32; o > 0; o >>= 1) cnt += __shfl_down(cnt, o, 64);
    if ((tid & 63) == 0) sh[tid >> 6] = cnt;
    __syncthreads();
    if (tid == 0) flag[0] = (sh[0] + sh[1] + sh[2] + sh[3] > 2048) ? 1 : 0;
}

// ---------------- LayerNorm (D=1024, one 256-thread block per row) ---------
template <bool RAW_IN>
__global__ void ln_kernel(const void* __restrict__ x, const void* __restrict__ g,
                          const void* __restrict__ b, u16* __restrict__ out,
                          const int* __restrict__ flagp) {
    const int isbf = *flagp;
    const int inbf = RAW_IN ? isbf : 1;
    const long base = (long)blockIdx.x * 1024;
    const int tid = threadIdx.x;
    float v[4];
    #pragma unroll
    for (int j = 0; j < 4; j++) v[j] = loadIn(x, base + tid + 256 * j, inbf);
    float mu = blockReduce<false>(v[0] + v[1] + v[2] + v[3]) * (1.0f / 1024.0f);
    float d[4], sq = 0.f;
    #pragma unroll
    for (int j = 0; j < 4; j++) { d[j] = v[j] - mu; sq += d[j] * d[j]; }
    float var = blockReduce<false>(sq) * (1.0f / 1024.0f);
    float rstd = rsqrtf(var + 1e-5f);
    #pragma unroll
    for (int j = 0; j < 4; j++) {
        int c = tid + 256 * j;
        out[base + c] = f2bf(d[j] * rstd * loadIn(g, c, isbf) + loadIn(b, c, isbf));
    }
}

// ---------------- 32x32 transpose -> bf16 ----------------------------------
__global__ void transpose_to_bf16(const void* __restrict__ in, int ldin, long inBatch,
                                  u16* __restrict__ out, int ldout, long outBatch,
                                  const int* __restrict__ flagp) {
    __shared__ u16 tile[32][33];
    const int isbf = flagp ? *flagp : 1;
    const long ibase = (long)blockIdx.z * inBatch;
    out += (long)blockIdx.z * outBatch;
    const int bc = blockIdx.x * 32, br = blockIdx.y * 32;
    const int tx = threadIdx.x & 31, ty = threadIdx.x >> 5;   // 256 thr
    #pragma unroll
    for (int i = 0; i < 32; i += 8)
        tile[ty + i][tx] = f2bf(loadIn(in, ibase + (long)(br + ty + i) * ldin + bc + tx, isbf));
    __syncthreads();
    #pragma unroll
    for (int i = 0; i < 32; i += 8)
        out[(long)(bc + ty + i) * ldout + br + tx] = tile[tx][ty + i];
}

// ---------------- BMx256 barrier-free-interior GEMM ------------------------
// C[M,N] = A[M,K] @ (Bt[N,K])^T (+epilogue). M%BM==0, N%256==0, K%64==0.
// 512 threads = 8 waves (2M x 4N), per-wave C tile (BM/2)x64.
// LDS: 2 K-tile slots x (A BMx64 + B 256x64) bf16 (128 or 96 KiB).
// Swizzle: 16B granule g of row r stored at g^(r&7); LDS dest linear,
// global source column pre-swizzled (global_load_lds stays direct).
// Per K-tile u: stage ALL of tile u+1 -> slot sn at tile top; barrier-free
// snake micro-phases (8 MFMA each) with frag reads one phase ahead under
// counted lgkm; boundary barrier+vmcnt(0)+barrier; prefetch next A-q0+bJ0.
// MODE: 0 qkv +bias->bf16   1 scores *scale->bf16   2 pv plain->bf16
//       3 proj +bias+res(raw)->bf16   4 fc +bias,gelu->bf16
//       5 fc2 +bias+res(bf16)->flag dtype
// CAUSAL: 0 none (T1 XCD swizzle), 1 triangular tile enum (BM=256 only),
//         2 K clamp to m0+BM (pv)
template <int MODE, int CAUSAL, int BM>
__global__ __launch_bounds__(512, 2) void gemm_8ph(
        const u16* __restrict__ A, int lda, long aBatch,
        const u16* __restrict__ Bt, int ldb, long bBatch,
        const void* __restrict__ bias,
        void* __restrict__ Cv, int ldc, long cBatch,
        const void* __restrict__ res,
        float scale, const int* __restrict__ flagp, int K) {
    constexpr int AQ = BM / 64;                     // A stage chunks / quads
    constexpr int MI = BM / 32;                     // acc M frags per wave
    __shared__ __align__(16) u16 sA[2][BM * 64];
    __shared__ __align__(16) u16 sB[2][256 * 64];

    int m0, n0;
    if (CAUSAL == 1) {
        // enumerate lower-triangular 256^2 tiles: bx -> (ti, tj), tj <= ti
        const int bx = blockIdx.x;
        int ti = (int)((sqrtf(8.0f * bx + 1.0f) - 1.0f) * 0.5f);
        while ((ti + 1) * (ti + 2) / 2 <= bx) ++ti;
        while (ti * (ti + 1) / 2 > bx) --ti;
        m0 = ti * 256;
        n0 = (bx - ti * (ti + 1) / 2) * 256;
    } else if (CAUSAL == 2) {
        m0 = (gridDim.y - 1 - blockIdx.y) * BM;    // big-NT blocks dispatch first
        n0 = blockIdx.x * 256;
    } else {
        // T1: bijective XCD chunk swizzle (launches have nwg % 8 == 0)
        const int gx  = gridDim.x;
        const int nwg = gx * gridDim.y;
        const int fid = blockIdx.y * gx + blockIdx.x;
        const int swz = (fid & 7) * (nwg >> 3) + (fid >> 3);
        m0 = (swz / gx) * BM;
        n0 = (swz % gx) * 256;
    }
    const int bz = blockIdx.z;
    A  += (long)bz * aBatch;
    Bt += (long)bz * bBatch;

    const int tid  = threadIdx.x;
    const int lane = tid & 63, wv = tid >> 6;
    const int wm = wv >> 2, wn = wv & 3;            // 2 x 4 wave grid
    const int l16 = lane & 15, quad = lane >> 4;
    const int xg = l16 & 7;                         // read-side granule XOR

    // staging mapping: 512 threads cover 64 rows x 8 granules, linear dest
    const int rq   = tid >> 3;                      // 0..63
    const int gsrc = ((tid & 7) ^ (rq & 7)) * 8;    // pre-swizzled source col
    const int gdst = (tid & 7) * 8;                 // linear dest granule
    const int rAb  = (rq < 32) ? rq : 96 + rq;      // A rows (BM=256 chunking)

    int NT = K >> 6;
    if (CAUSAL == 2) NT = min(K, m0 + BM) >> 6;     // probs zero past t|255

#define STAGE_A(t_, q_) do {                                                     \
        const int sl_ = (t_) & 1;                                               \
        const int k0_ = (t_) << 6;                                              \
        const int ra_ = (BM == 256) ? (((q_) << 5) + rAb) : (((q_) << 6) + rq); \
        GLOAD_LDS16(A + (long)(m0 + ra_) * lda + k0_ + gsrc,                    \
                    &sA[sl_][ra_ * 64 + gdst]);                                 \
    } while (0)

#define STAGE_B(t_, q_) do {                                                     \
        const int sl_ = (t_) & 1;                                               \
        const int k0_ = (t_) << 6;                                              \
        const int rb_ = ((q_) << 6) + rq;                                       \
        GLOAD_LDS16(Bt + (long)(n0 + rb_) * ldb + k0_ + gsrc,                   \
                    &sB[sl_][rb_ * 64 + gdst]);                                 \
    } while (0)

#define STAGE_ALL(t_) do {                                                       \
        _Pragma("unroll")                                                       \
        for (int q_ = 0; q_ < AQ; ++q_) STAGE_A(t_, q_);                        \
        _Pragma("unroll")                                                       \
        for (int q_ = 0; q_ < 4; ++q_) STAGE_B(t_, q_);                         \
    } while (0)

#define BAR8() asm volatile("s_barrier" ::: "memory")

#define WVMC(n_) do {                                                            \
        asm volatile("s_waitcnt vmcnt(" #n_ ")" ::: "memory");                   \
        __builtin_amdgcn_sched_barrier(0); } while (0)

#define WLGKM(n_) do {                                                           \
        asm volatile("s_waitcnt lgkmcnt(" #n_ ")" ::: "memory");                 \
        __builtin_amdgcn_sched_barrier(0); } while (0)

    // A quadrant reads for quad qn_ (4x b128) into buf_[2][2]
#define RD_A4(buf_, qn_, sl_) do {                                               \
        DSR128(buf_[0][0], &sA[sl_][(wm * (BM / 2) + (2 * (qn_) + 0) * 16 + l16) * 64 \
                                    + (((0 * 4 + quad) ^ xg) * 8)]);             \
        DSR128(buf_[0][1], &sA[sl_][(wm * (BM / 2) + (2 * (qn_) + 0) * 16 + l16) * 64 \
                                    + (((1 * 4 + quad) ^ xg) * 8)]);             \
        DSR128(buf_[1][0], &sA[sl_][(wm * (BM / 2) + (2 * (qn_) + 1) * 16 + l16) * 64 \
                                    + (((0 * 4 + quad) ^ xg) * 8)]);             \
        DSR128(buf_[1][1], &sA[sl_][(wm * (BM / 2) + (2 * (qn_) + 1) * 16 + l16) * 64 \
                                    + (((1 * 4 + quad) ^ xg) * 8)]);             \
    } while (0)

    // B half jp_ (j = 2*jp_, 2*jp_+1): 4x b128 into buf_[2][2]
#define RD_B4(buf_, jp_, sl_) do {                                               \
        DSR128(buf_[0][0], &sB[sl_][(wn * 64 + (2 * (jp_) + 0) * 16 + l16) * 64  \
                                    + (((0 * 4 + quad) ^ xg) * 8)]);             \
        DSR128(buf_[0][1], &sB[sl_][(wn * 64 + (2 * (jp_) + 0) * 16 + l16) * 64  \
                                    + (((1 * 4 + quad) ^ xg) * 8)]);             \
        DSR128(buf_[1][0], &sB[sl_][(wn * 64 + (2 * (jp_) + 1) * 16 + l16) * 64  \
                                    + (((0 * 4 + quad) ^ xg) * 8)]);             \
        DSR128(buf_[1][1], &sB[sl_][(wn * 64 + (2 * (jp_) + 1) * 16 + l16) * 64  \
                                    + (((1 * 4 + quad) ^ xg) * 8)]);             \
    } while (0)

    // 8 MFMA: acc[2*mq_+f][2*jp_+jj] += A_[f][s] * B_[jj][s]
    // s=0 group first (4 independent), then s=1 (dep distance 4). T5 setprio.
#define MFMA8(mq_, jp_, A_, B_) do {                                             \
        __builtin_amdgcn_s_setprio(1);                                          \
        _Pragma("unroll")                                                        \
        for (int f_ = 0; f_ < 2; ++f_)                                           \
            _Pragma("unroll")                                                    \
            for (int jj_ = 0; jj_ < 2; ++jj_)                                    \
                acc[2 * (mq_) + f_][2 * (jp_) + jj_] =                           \
                    __builtin_amdgcn_mfma_f32_16x16x32_bf16(                     \
                        A_[f_][0], B_[jj_][0],                                   \
                        acc[2 * (mq_) + f_][2 * (jp_) + jj_], 0, 0, 0);          \
        _Pragma("unroll")                                                        \
        for (int f_ = 0; f_ < 2; ++f_)                                           \
            _Pragma("unroll")                                                    \
            for (int jj_ = 0; jj_ < 2; ++jj_)                                    \
                acc[2 * (mq_) + f_][2 * (jp_) + jj_] =                           \
                    __builtin_amdgcn_mfma_f32_16x16x32_bf16(                     \
                        A_[f_][1], B_[jj_][1],                                   \
                        acc[2 * (mq_) + f_][2 * (jp_) + jj_], 0, 0, 0);          \
        __builtin_amdgcn_s_setprio(0);                                          \
    } while (0)

    f32x4 acc[MI][4];
    #pragma unroll
    for (int i = 0; i < MI; i++)
        #pragma unroll
        for (int j = 0; j < 4; j++) acc[i][j] = f32x4{0.f, 0.f, 0.f, 0.f};

    bf16x8 afA[2][2], afB[2][2], bJ0[2][2], bJ1[2][2];

    // prologue: stage tile 0 into slot 0; confirm; prefetch A-q0 + B-half0.
    STAGE_ALL(0);
    WVMC(0);
    BAR8();
    RD_A4(afA, 0, 0);
    RD_B4(bJ0, 0, 0);

    for (int u = 0; u < NT; ++u) {
        const int su = u & 1, sn = su ^ 1;
        // tile top: stage ALL of tile u+1 into slot sn (never read this tile)
        if (u + 1 < NT) STAGE_ALL(u + 1);
        if (BM == 256) {
            // 8 micro-phases, snake (mq,jp)
            RD_B4(bJ1, 1, su);
            WLGKM(4); MFMA8(0, 0, afA, bJ0);
            RD_A4(afB, 1, su);
            WLGKM(4); MFMA8(0, 1, afA, bJ1);
            WLGKM(0); MFMA8(1, 1, afB, bJ1);
            RD_A4(afA, 2, su);
            WLGKM(4); MFMA8(1, 0, afB, bJ0);
            WLGKM(0); MFMA8(2, 0, afA, bJ0);
            RD_A4(afB, 3, su);
            WLGKM(4); MFMA8(2, 1, afA, bJ1);
            WLGKM(0); MFMA8(3, 1, afB, bJ1);
            MFMA8(3, 0, afB, bJ0);
        } else {
            // 4 micro-phases, snake (mq,jp) over 2x2
            RD_B4(bJ1, 1, su);
            WLGKM(4); MFMA8(0, 0, afA, bJ0);
            RD_A4(afB, 1, su);
            WLGKM(4); MFMA8(0, 1, afA, bJ1);
            WLGKM(0); MFMA8(1, 1, afB, bJ1);
            MFMA8(1, 0, afB, bJ0);
        }
        // boundary: all waves' reads of sn's old data are done (each wave's
        // lgkm wait preceded its barrier arrival) -> safe to expose staging.
        BAR8();
        WVMC(0);                       // own tile-top stages landed (~free)
        BAR8();                        // everyone's landed
        if (u + 1 < NT) {              // prefetch next tile's first frags
            RD_A4(afA, 0, sn);
            RD_B4(bJ0, 0, sn);
        }
    }
    WLGKM(0);                          // quiesce before frag-reg reuse

    const int isbf = (MODE == 0 || MODE == 3 || MODE == 4 || MODE == 5) ? *flagp : 1;
    #pragma unroll
    for (int mi = 0; mi < MI; ++mi) {
        #pragma unroll
        for (int j = 0; j < 4; ++j) {
            #pragma unroll
            for (int r = 0; r < 4; ++r) {
                const int row = m0 + wm * (BM / 2) + mi * 16 + quad * 4 + r;
                const int col = n0 + wn * 64 + j * 16 + l16;
                const long idx = (long)bz * cBatch + (long)row * ldc + col;
                float v = acc[mi][j][r];
                if (MODE == 1) {
                    reinterpret_cast<u16*>(Cv)[idx] = f2bf(v * scale);
                } else if (MODE == 2) {
                    reinterpret_cast<u16*>(Cv)[idx] = f2bf(v);
                } else {
                    v += loadIn(bias, col, isbf);
                    if (MODE == 4) v = gelu_fast(v);
                    if (MODE == 3) v += loadIn(res, (long)row * ldc + col, isbf);
                    if (MODE == 5) v += bf2f(((const u16*)res)[(long)row * ldc + col]);
                    if (MODE == 5 && !isbf)
                        reinterpret_cast<float*>(Cv)[idx] = v;
                    else
                        reinterpret_cast<u16*>(Cv)[idx] = f2bf(v);
                }
            }
        }
    }
#undef STAGE_A
#undef STAGE_B
#undef STAGE_ALL
#undef BAR8
#undef WVMC
#undef WLGKM
#undef RD_A4
#undef RD_B4
#undef MFMA8
}

// ---------------- causal softmax: bf16 scores -> bf16 probs ----------------
// Row r: valid cols <= t=r&2047. PV tiles (BM=128, Keff = m0+128 clamp) read
// cols < (t|127)+1 <= (t|255)+1, so zeros are stored out to t|255.
__global__ void softmax_causal(const u16* __restrict__ S, u16* __restrict__ P) {
    const long row = blockIdx.x;
    const int t = (int)(row & 2047);
    const u16* sr = S + row * 2048;
    u16* pr = P + row * 2048;
    const int tid = threadIdx.x;
    const int s0 = tid * 8;
    float v[8];
    float mx = -INFINITY;
    if (s0 <= t) {
        u16x8 raw = *reinterpret_cast<const u16x8*>(sr + s0);
        #pragma unroll
        for (int i = 0; i < 8; i++) {
            float x = bf2f(raw[i]);
            v[i] = (s0 + i <= t) ? x : -INFINITY;
            mx = fmaxf(mx, v[i]);
        }
    } else {
        #pragma unroll
        for (int i = 0; i < 8; i++) v[i] = -INFINITY;
    }
    mx = blockReduce<true>(mx);
    float sum = 0.f;
    #pragma unroll
    for (int i = 0; i < 8; i++) {
        float e = (v[i] == -INFINITY) ? 0.0f : __expf(v[i] - mx);
        v[i] = e;
        sum += e;
    }
    sum = blockReduce<false>(sum);
    float inv = 1.0f / sum;
    if (s0 <= (t | 255)) {
        u16x8 o;
        #pragma unroll
        for (int i = 0; i < 8; i++) o[i] = f2bf(v[i] * inv);
        *reinterpret_cast<u16x8*>(pr + s0) = o;
    }
}

// ---------------------------------------------------------------------------
extern "C" void kernel_launch(void* const* d_in, const int* in_sizes, int n_in,
                              void* d_out, int out_size, void* d_ws, size_t ws_size,
                              hipStream_t stream) {
    const void* x      = d_in[0];
    const void* w_attn = d_in[1];
    const void* b_attn = d_in[2];
    const void* w_proj = d_in[3];
    const void* b_proj = d_in[4];
    const void* ln1_g  = d_in[5];
    const void* ln1_b  = d_in[6];
    const void* ln2_g  = d_in[7];
    const void* ln2_b  = d_in[8];
    const void* w_fc   = d_in[9];
    const void* b_fc   = d_in[10];
    const void* w_fc2  = d_in[11];
    const void* b_fc2  = d_in[12];

    // workspace layout (176.16 MB + flag)
    char* ws = (char*)d_ws;
    u16*   hbuf   = (u16*)(ws);                      // 16.78 MB: h -> y -> h2
    u16*   qkv    = (u16*)(ws + 16777216);           // 50.33 MB (later: probs+x1)
    u16*   S      = (u16*)(ws + 67108864);           // 64 MB scores (later: g1)
    u16*   wattnT = (u16*)(ws + 134217728);          // 25.17 MB of w^T
    u16*   wprojT = wattnT + 3072 * 1024;
    u16*   wfcT   = wprojT + 1024 * 1024;
    u16*   wfc2T  = wfcT + 4096 * 1024;
    u16*   vT     = wfc2T + 1024 * 4096;             // 16.78 MB
    int*   flag   = (int*)(ws + 176160768);
    u16*   probs  = qkv;                   // reuses qkv region after scores
    u16*   x1     = qkv + 16777216;

    detect_dtype<<<1, 256, 0, stream>>>((const u16*)x, flag);

    // weight transposes (raw dtype -> bf16)
    transpose_to_bf16<<<dim3(96, 32, 1),  256, 0, stream>>>(w_attn, 3072, 0, wattnT, 1024, 0, flag);
    transpose_to_bf16<<<dim3(32, 32, 1),  256, 0, stream>>>(w_proj, 1024, 0, wprojT, 1024, 0, flag);
    transpose_to_bf16<<<dim3(128, 32, 1), 256, 0, stream>>>(w_fc,   4096, 0, wfcT,   1024, 0, flag);
    transpose_to_bf16<<<dim3(32, 128, 1), 256, 0, stream>>>(w_fc2,  1024, 0, wfc2T,  4096, 0, flag);

    // h = LN1(x)
    ln_kernel<true><<<8192, 256, 0, stream>>>(x, ln1_g, ln1_b, hbuf, flag);

    // qkv = h @ w_attn + b_attn       [8192, 3072]   BM=256
    gemm_8ph<0, 0, 256><<<dim3(12, 32, 1), 512, 0, stream>>>(
        hbuf, 1024, 0, wattnT, 1024, 0, b_attn, qkv, 3072, 0, nullptr, 0.f, flag, 1024);

    // vT[b] = V[b]^T                   [1024, 2048] x4
    transpose_to_bf16<<<dim3(32, 64, 4), 256, 0, stream>>>(
        qkv + 2048, 3072, (long)2048 * 3072, vT, 2048, (long)1024 * 2048, nullptr);

    // S[b] = 0.125 * q[b] @ k[b]^T    lower-tri 256^2 tiles (36 per batch)
    gemm_8ph<1, 1, 256><<<dim3(36, 1, 4), 512, 0, stream>>>(
        qkv, 3072, (long)2048 * 3072, qkv + 1024, 3072, (long)2048 * 3072,
        nullptr, S, 2048, (long)2048 * 2048, nullptr, 0.125f, flag, 1024);

    // probs = causal softmax(S)  (stores zeros out to t|255)
    softmax_causal<<<8192, 256, 0, stream>>>(S, probs);

    // y[b] = P[b] @ V[b]              [2048, 1024] x4, BM=128, K clamp m0+128
    gemm_8ph<2, 2, 128><<<dim3(4, 16, 4), 512, 0, stream>>>(
        probs, 2048, (long)2048 * 2048, vT, 2048, (long)1024 * 2048,
        nullptr, hbuf, 1024, (long)2048 * 1024, nullptr, 0.f, flag, 2048);

    // x1 = x + y @ w_proj + b_proj    (bf16, in ws)   BM=128, 256 blocks
    gemm_8ph<3, 0, 128><<<dim3(4, 64, 1), 512, 0, stream>>>(
        hbuf, 1024, 0, wprojT, 1024, 0, b_proj, x1, 1024, 0, x, 0.f, flag, 1024);

    // h2 = LN2(x1) -> hbuf
    ln_kernel<false><<<8192, 256, 0, stream>>>(x1, ln2_g, ln2_b, hbuf, flag);

    // g1 = gelu(h2 @ w_fc + b_fc)     [8192, 4096] bf16 in S region   BM=256
    gemm_8ph<4, 0, 256><<<dim3(16, 32, 1), 512, 0, stream>>>(
        hbuf, 1024, 0, wfcT, 1024, 0, b_fc, S, 4096, 0, nullptr, 0.f, flag, 1024);

    // out = x1 + g1 @ w_fc2 + b_fc2   (detected dtype)   BM=128, 256 blocks
    gemm_8ph<5, 0, 128><<<dim3(4, 64, 1), 512, 0, stream>>>(
        S, 4096, 0, wfc2T, 4096, 0, b_fc2, d_out, 1024, 0, x1, 0.f, flag, 4096);
}